// Round 13
// baseline (192.392 us; speedup 1.0000x reference)
//
#include <hip/hip_runtime.h>
#include <hip/hip_bf16.h>
#include <stdint.h>

#define DEVFN static __device__ __forceinline__

typedef __attribute__((ext_vector_type(8))) short bf16x8;
typedef __attribute__((ext_vector_type(4))) short s16x4;
typedef __attribute__((ext_vector_type(4))) float f32x4;

static constexpr int TOK = 8192;       // B*N
static constexpr int DIM = 768;
static constexpr int HEADS = 8;
static constexpr int HD = 96;
static constexpr int EXPERTS = 24;
static constexpr int NQ = 2304;        // EXPERTS*HD
static constexpr int NQP = 2560;       // NQ + 192 (kv) + 64 (zero pad)
static constexpr float C2 = 0.14724484f;   // HD^-0.5 * log2(e)
static constexpr float THRRAW = 78.0f;     // defer-max threshold, raw-score units

// ---- workspace layout (bytes) ----
static constexpr size_t OFF_XB   = 0;          // x bf16 [8192][768]   (o aliases)
static constexpr size_t OFF_BT1  = 12582912;   // Bt1 bf16 [2560][768]
static constexpr size_t OFF_W2T  = 16515072;   // W2t bf16 [768][2304]
static constexpr size_t OFF_K    = 20054016;   // KVp bf16 [256 tiles][6144]: K 12x32x8 | V 4x96x8
static constexpr size_t OFF_GATE = 23199744;   // gates f32 [8192][8]
static constexpr size_t OFF_TOPI = 23461888;   // topi i32 [8192][8]
static constexpr size_t OFF_AUX  = 23724032;   // me[24], fe[24], z
static constexpr size_t OFF_ALLQ = 23724288;   // allq bf16 [8192][2560]
// gating partials [16][24][8192] f32 = 12.58 MB + logitsT [24][8192] f32 = 0.79 MB,
// both alias into ALLQ region (dead before gemm1 writes allq)
static constexpr size_t OFF_PART = OFF_ALLQ;
static constexpr size_t OFF_LOGT = OFF_ALLQ + 12582912;

DEVFN short f2bf(float f){
  __hip_bfloat16 h = __float2bfloat16(f);
  return __builtin_bit_cast(short, h);
}
DEVFN float bf2f(short u){
  return __bfloat162float(__builtin_bit_cast(__hip_bfloat16, u));
}

DEVFN void gload16(const void* g, void* l){
  auto gp = reinterpret_cast<__attribute__((address_space(1))) unsigned int*>(
      reinterpret_cast<uintptr_t>(g));
  auto lp = reinterpret_cast<__attribute__((address_space(3))) unsigned int*>(
      reinterpret_cast<uintptr_t>(l));
  __builtin_amdgcn_global_load_lds(gp, lp, 16, 0, 0);
}

// ---------------- prep v2: LDS tile transposes, coalesced both sides ----------------
__global__ __launch_bounds__(256) void prep_kernel(const float* __restrict__ W1,
                                                   const float* __restrict__ Wkv,
                                                   const float* __restrict__ W2,
                                                   short* __restrict__ Bt1,
                                                   short* __restrict__ W2t){
  __shared__ float tl[6240];
  int bid = blockIdx.x, tid = threadIdx.x;

  if (bid < 288){
    // W1[e][768][96] -> Bt1[e*96+hh][768]; tile: 64 d x 96 hh
    int e = bid / 12, dt = bid - e*12;
    int d0 = dt*64;
    const float* src = W1 + (size_t)e*(DIM*HD);
#pragma unroll
    for (int it = 0; it < 6; ++it){
      int c = it*256 + tid;
      int row = c / 24, q = c - row*24;
      float4 v = *reinterpret_cast<const float4*>(src + (size_t)(d0+row)*HD + q*4);
      float* dst = &tl[row*97 + q*4];
      dst[0]=v.x; dst[1]=v.y; dst[2]=v.z; dst[3]=v.w;
    }
    __syncthreads();
#pragma unroll
    for (int it = 0; it < 6; ++it){
      int c = it*256 + tid;
      int hh = c >> 4, cq = c & 15;
      s16x4 o4;
#pragma unroll
      for (int j = 0; j < 4; ++j) o4[j] = f2bf(tl[(cq*4+j)*97 + hh]);
      *reinterpret_cast<s16x4*>(Bt1 + (size_t)(e*HD + hh)*DIM + d0 + cq*4) = o4;
    }
  } else if (bid < 312){
    // Wkv[768][192] -> Bt1[NQ+j][768]; tile: 64 d x 96 j
    int t = bid - 288;
    int jb = t / 12, dt = t - jb*12;
    int j0 = jb*96, d0 = dt*64;
#pragma unroll
    for (int it = 0; it < 6; ++it){
      int c = it*256 + tid;
      int row = c / 24, q = c - row*24;
      float4 v = *reinterpret_cast<const float4*>(Wkv + (size_t)(d0+row)*192 + j0 + q*4);
      float* dst = &tl[row*97 + q*4];
      dst[0]=v.x; dst[1]=v.y; dst[2]=v.z; dst[3]=v.w;
    }
    __syncthreads();
#pragma unroll
    for (int it = 0; it < 6; ++it){
      int c = it*256 + tid;
      int jj = c >> 4, cq = c & 15;
      s16x4 o4;
#pragma unroll
      for (int j = 0; j < 4; ++j) o4[j] = f2bf(tl[(cq*4+j)*97 + jj]);
      *reinterpret_cast<s16x4*>(Bt1 + (size_t)(NQ + j0 + jj)*DIM + d0 + cq*4) = o4;
    }
  } else if (bid < 600){
    // W2[e][96][768] -> W2t[c][e*96+hh]; tile: 96 hh x 64 c
    int t = bid - 312;
    int e = t / 12, ct = t - e*12;
    int c0 = ct*64;
    const float* src = W2 + (size_t)e*(HD*DIM);
#pragma unroll
    for (int it = 0; it < 6; ++it){
      int c = it*256 + tid;
      int hh = c >> 4, q = c & 15;
      float4 v = *reinterpret_cast<const float4*>(src + (size_t)hh*DIM + c0 + q*4);
      float* dst = &tl[hh*65 + q*4];
      dst[0]=v.x; dst[1]=v.y; dst[2]=v.z; dst[3]=v.w;
    }
    __syncthreads();
#pragma unroll
    for (int it = 0; it < 6; ++it){
      int c = it*256 + tid;
      int cr = c / 24, q = c - cr*24;
      s16x4 o4;
#pragma unroll
      for (int j = 0; j < 4; ++j) o4[j] = f2bf(tl[(q*4+j)*65 + cr]);
      *reinterpret_cast<s16x4*>(W2t + (size_t)(c0 + cr)*NQ + e*HD + q*4) = o4;
    }
  } else {
    // zero pad rows [NQ+192, NQP) of Bt1
    int i = (bid-600)*256 + tid;         // 64*768 = 49152
    Bt1[(size_t)(NQ + 192)*DIM + i] = 0;
  }
}

// ---------------- gating G1: logit partials, lane=token, W via scalar pipe ----------------
__global__ __launch_bounds__(64) void gating_partial(const float* __restrict__ x,
                                                     const float* __restrict__ Wg,
                                                     const int* __restrict__ task,
                                                     short* __restrict__ xb,
                                                     float* __restrict__ partial){
  __shared__ float xl[64*49];
  int lane = threadIdx.x;
  int tg = blockIdx.x >> 4, kc = blockIdx.x & 15;
  int tok0 = tg*64, kbase = kc*48;
  const float* Wt = Wg + (size_t)task[0]*(DIM*EXPERTS) + (size_t)kbase*EXPERTS;

#pragma unroll
  for (int i = 0; i < 12; ++i){
    int c = i*64 + lane;
    int t = c / 12, cc = c - t*12;
    size_t gidx = (size_t)(tok0+t)*DIM + kbase + cc*4;
    float4 v = *reinterpret_cast<const float4*>(x + gidx);
    float* dst = &xl[t*49 + cc*4];
    dst[0] = v.x; dst[1] = v.y; dst[2] = v.z; dst[3] = v.w;
    s16x4 o4;
    o4[0] = f2bf(v.x); o4[1] = f2bf(v.y); o4[2] = f2bf(v.z); o4[3] = f2bf(v.w);
    *reinterpret_cast<s16x4*>(xb + gidx) = o4;
  }
  __syncthreads();

  float acc[EXPERTS];
#pragma unroll
  for (int e = 0; e < EXPERTS; ++e) acc[e] = 0.f;
  for (int d = 0; d < 48; ++d){
    float xv = xl[lane*49 + d];
    const float* wr = Wt + d*EXPERTS;  // wave-uniform address -> scalar loads
#pragma unroll
    for (int e = 0; e < EXPERTS; ++e) acc[e] = fmaf(xv, wr[e], acc[e]);
  }
#pragma unroll
  for (int e = 0; e < EXPERTS; ++e)
    partial[(size_t)(kc*EXPERTS + e)*TOK + tok0 + lane] = acc[e];
}

// ---------------- gating G2a: combine partials over kc ----------------
__global__ __launch_bounds__(256) void gating_combine(const float* __restrict__ partial,
                                                      float* __restrict__ logT){
  int idx = blockIdx.x*256 + threadIdx.x;      // [e][token] linear, 24*8192
  float s = 0.f;
#pragma unroll
  for (int kc = 0; kc < 16; ++kc)
    s += partial[(size_t)kc*EXPERTS*TOK + idx];  // ascending kc: deterministic
  logT[idx] = s;
}

// ---------------- gating G2b: top-8 select + gates + aux ----------------
__global__ __launch_bounds__(256) void gating_select(const float* __restrict__ logT,
                                                     int* __restrict__ topi,
                                                     float* __restrict__ gates,
                                                     float* __restrict__ auxbuf){
  __shared__ float lme[EXPERTS];
  __shared__ float lfr[EXPERTS];
  __shared__ float lz;
  int tid = threadIdx.x;
  int lane = tid & 63;
  int token = blockIdx.x*256 + tid;
  if (tid < EXPERTS){ lme[tid] = 0.f; lfr[tid] = 0.f; }
  if (tid == 0) lz = 0.f;
  __syncthreads();

  float acc[EXPERTS];
#pragma unroll
  for (int e = 0; e < EXPERTS; ++e)
    acc[e] = logT[(size_t)e*TOK + token];

  float mx = acc[0];
#pragma unroll
  for (int e = 1; e < EXPERTS; ++e) mx = fmaxf(mx, acc[e]);
  unsigned selm = 0; int sel[8]; float sg[8];
#pragma unroll
  for (int t = 0; t < 8; ++t){
    float best = -3.0e38f; int bi = 0;
#pragma unroll
    for (int e = 0; e < EXPERTS; ++e){
      bool ok = !((selm>>e)&1u) && (acc[e] > best);
      best = ok ? acc[e] : best;
      bi   = ok ? e      : bi;
    }
    selm |= (1u<<bi); sel[t] = bi; sg[t] = best;
  }

  float p[EXPERTS]; float S = 0.f;
#pragma unroll
  for (int e = 0; e < EXPERTS; ++e){ p[e] = __expf(acc[e] - mx); S += p[e]; }
  float lse = mx + __logf(S);
  float Sinv = 1.f/S;
  float gsum = 0.f; float pg[8];
#pragma unroll
  for (int t = 0; t < 8; ++t){ pg[t] = __expf(sg[t] - mx)*Sinv; gsum += pg[t]; }
  float dinv = 1.f/(gsum + 1e-6f);

#pragma unroll
  for (int t = 0; t < 8; ++t){
    topi[token*HEADS + t]  = sel[t];
    gates[token*HEADS + t] = pg[t]*dinv;
  }

  float z2 = lse*lse;
#pragma unroll
  for (int d = 1; d < 64; d <<= 1) z2 += __shfl_xor(z2, d, 64);
#pragma unroll
  for (int e = 0; e < EXPERTS; ++e){
    float v = p[e]*Sinv;
#pragma unroll
    for (int d = 1; d < 64; d <<= 1) v += __shfl_xor(v, d, 64);
    bool hit = (sel[0]==e)|(sel[1]==e)|(sel[2]==e)|(sel[3]==e)|
               (sel[4]==e)|(sel[5]==e)|(sel[6]==e)|(sel[7]==e);
    unsigned long long bal = __ballot(hit);
    if (lane == 0){
      atomicAdd(&lme[e], v);
      atomicAdd(&lfr[e], (float)__popcll(bal));
    }
  }
  if (lane == 0) atomicAdd(&lz, z2);
  __syncthreads();
  if (tid < EXPERTS){
    atomicAdd(&auxbuf[tid], lme[tid]);
    atomicAdd(&auxbuf[EXPERTS + tid], lfr[tid]);
  } else if (tid == 63) atomicAdd(&auxbuf[2*EXPERTS], lz);
}

__global__ void aux_final(const float* __restrict__ auxbuf, float* __restrict__ outa){
  if (threadIdx.x != 0 || blockIdx.x != 0) return;
  float ms = 0.f, fs = 0.f;
  for (int e=0;e<EXPERTS;++e){ ms += auxbuf[e]; fs += auxbuf[EXPERTS+e]; }
  float sw = 0.f;
  for (int e=0;e<EXPERTS;++e) sw += (auxbuf[e]/ms)*(auxbuf[EXPERTS+e]/fs);
  sw *= (float)EXPERTS;
  float z = auxbuf[2*EXPERTS] / (float)TOK;
  outa[0] = 0.1f*sw + 0.001f*z;
}

// ---------------- bf16 MFMA GEMM: 128x128 tile, XCD swizzle, T2 LDS swizzle ----------------
template<bool OUT_BF16>
__global__ __launch_bounds__(256) void gemm_bt(const short* __restrict__ A,
                                               const short* __restrict__ Bt,
                                               void* __restrict__ Cout,
                                               int M, int N, int K){
  __shared__ short As[128*64];
  __shared__ short Bs[128*64];
  int nwg = gridDim.x*gridDim.y;
  int orig = blockIdx.y*gridDim.x + blockIdx.x;
  int cpx = nwg >> 3;
  int swz = (orig & 7)*cpx + (orig >> 3);   // requires nwg % 8 == 0
  int bx = swz % gridDim.x, by = swz / gridDim.x;

  int tid = threadIdx.x;
  int lane = tid & 63, w = tid >> 6;
  int wr = w >> 1, wc = w & 1;
  int l15 = lane & 15, lg = lane >> 4;
  int m0 = by * 128, n0 = bx * 128;

  f32x4 acc[4][4] = {};

  for (int k0 = 0; k0 < K; k0 += 64){
#pragma unroll
    for (int it = 0; it < 4; ++it){
      int c = it*256 + tid;
      int row = c >> 3, cc = c & 7;
      int csrc = cc ^ (row & 7);
      gload16(A  + (size_t)(m0+row)*K + k0 + csrc*8, (char*)As + (size_t)c*16);
      gload16(Bt + (size_t)(n0+row)*K + k0 + csrc*8, (char*)Bs + (size_t)c*16);
    }
    __syncthreads();
#pragma unroll
    for (int kk = 0; kk < 2; ++kk){
      bf16x8 af[4], bfr[4];
      int jp = (kk*4 + lg) ^ (l15 & 7);
#pragma unroll
      for (int m = 0; m < 4; ++m)
        af[m] = *reinterpret_cast<const bf16x8*>(&As[(wr*64 + m*16 + l15)*64 + jp*8]);
#pragma unroll
      for (int n = 0; n < 4; ++n)
        bfr[n] = *reinterpret_cast<const bf16x8*>(&Bs[(wc*64 + n*16 + l15)*64 + jp*8]);
#pragma unroll
      for (int m = 0; m < 4; ++m)
#pragma unroll
        for (int n = 0; n < 4; ++n)
          acc[m][n] = __builtin_amdgcn_mfma_f32_16x16x32_bf16(af[m], bfr[n], acc[m][n], 0, 0, 0);
    }
    __syncthreads();
  }
#pragma unroll
  for (int m = 0; m < 4; ++m)
#pragma unroll
    for (int n = 0; n < 4; ++n){
      int rbase = m0 + wr*64 + m*16 + lg*4;
      int col   = n0 + wc*64 + n*16 + l15;
#pragma unroll
      for (int r = 0; r < 4; ++r){
        float v = acc[m][n][r];
        size_t idx = (size_t)(rbase + r)*N + col;
        if constexpr (OUT_BF16) ((short*)Cout)[idx] = f2bf(v);
        else                    ((float*)Cout)[idx] = v;
      }
    }
}

// ---------------- GEMM2 fused: dbuf LDS + T14 async gather pipeline ----------------
__global__ __launch_bounds__(256) void gemm2_fused(const short* __restrict__ o,
                                                   const int* __restrict__ topi,
                                                   const short* __restrict__ W2t,
                                                   float* __restrict__ out){
  __shared__ short As[2][128*64];
  __shared__ short Bs[2][64*64];
  __shared__ signed char hmap[128][24];
  int nwg = gridDim.x*gridDim.y;
  int orig = blockIdx.y*gridDim.x + blockIdx.x;
  int cpx = nwg >> 3;
  int swz = (orig & 7)*cpx + (orig >> 3);
  int bx = swz % gridDim.x, by = swz / gridDim.x;

  int tid = threadIdx.x;
  int lane = tid & 63, w = tid >> 6;
  int l15 = lane & 15, lg = lane >> 4;
  int m0 = by * 128, n0 = bx * 64;

  int* hm32 = (int*)&hmap[0][0];
  for (int i = tid; i < 768; i += 256) hm32[i] = -1;
  __syncthreads();
  for (int i = tid; i < 128*8; i += 256){
    int row = i >> 3, hh = i & 7;
    int e = topi[(size_t)(m0+row)*HEADS + hh];
    hmap[row][e] = (signed char)hh;
  }
  __syncthreads();

  int arow[4], accv[4];
  size_t arbase[4];
#pragma unroll
  for (int it = 0; it < 4; ++it){
    int c = it*256 + tid;
    arow[it] = c >> 3; accv[it] = c & 7;
    arbase[it] = (size_t)(m0 + arow[it])*DIM;
  }

  f32x4 acc[2][4] = {};
  bf16x8 areg[4];

#define STAGE_A(kt, dst)                                                     \
  {                                                                          \
    _Pragma("unroll")                                                        \
    for (int it = 0; it < 4; ++it){                                          \
      unsigned kc = (unsigned)((kt)*8 + accv[it]);                           \
      unsigned e = kc / 12u;                                                 \
      unsigned dc = kc - e*12u;                                              \
      int hh = hmap[arow[it]][e];                                            \
      bf16x8 av = {};                                                        \
      if (hh >= 0)                                                           \
        av = *reinterpret_cast<const bf16x8*>(o + arbase[it] + hh*HD + dc*8);\
      dst[it] = av;                                                          \
    }                                                                        \
  }
#define WRITE_A(buf, src)                                                    \
  {                                                                          \
    _Pragma("unroll")                                                        \
    for (int it = 0; it < 4; ++it)                                           \
      *reinterpret_cast<bf16x8*>(                                            \
        &As[buf][arow[it]*64 + ((accv[it] ^ (arow[it] & 7)))*8]) = src[it];  \
  }
#define STAGE_B(kt, buf)                                                     \
  {                                                                          \
    _Pragma("unroll")                                                        \
    for (int it = 0; it < 2; ++it){                                          \
      int c = it*256 + tid;                                                  \
      int row = c >> 3, cc = c & 7;                                          \
      int csrc = cc ^ (row & 7);                                             \
      gload16(W2t + (size_t)(n0+row)*NQ + (kt)*64 + csrc*8,                  \
              (char*)&Bs[buf][0] + (size_t)c*16);                            \
    }                                                                        \
  }

  STAGE_A(0, areg);
  STAGE_B(0, 0);
  WRITE_A(0, areg);
  __syncthreads();

  for (int kt = 0; kt < 36; ++kt){
    int buf = kt & 1;
    bf16x8 anext[4];
    if (kt < 35){
      STAGE_A(kt+1, anext);
      STAGE_B(kt+1, buf^1);
    }
#pragma unroll
    for (int kk = 0; kk < 2; ++kk){
      int jp = (kk*4 + lg) ^ (l15 & 7);
      bf16x8 af[2], bfr[4];
#pragma unroll
      for (int m = 0; m < 2; ++m)
        af[m] = *reinterpret_cast<const bf16x8*>(&As[buf][(w*32 + m*16 + l15)*64 + jp*8]);
#pragma unroll
      for (int n = 0; n < 4; ++n)
        bfr[n] = *reinterpret_cast<const bf16x8*>(&Bs[buf][(n*16 + l15)*64 + jp*8]);
#pragma unroll
      for (int m = 0; m < 2; ++m)
#pragma unroll
        for (int n = 0; n < 4; ++n)
          acc[m][n] = __builtin_amdgcn_mfma_f32_16x16x32_bf16(af[m], bfr[n], acc[m][n], 0, 0, 0);
    }
    if (kt < 35) WRITE_A(buf^1, anext);
    __syncthreads();
  }
#undef STAGE_A
#undef WRITE_A
#undef STAGE_B

#pragma unroll
  for (int m = 0; m < 2; ++m)
#pragma unroll
    for (int n = 0; n < 4; ++n){
      int rbase = m0 + w*32 + m*16 + lg*4;
      int col   = n0 + n*16 + l15;
#pragma unroll
      for (int r = 0; r < 4; ++r)
        out[(size_t)(rbase + r)*DIM + col] = acc[m][n][r];
    }
}

// ---------------- split kv: bias + repack into combined 32-key tiles ----------------
// KVp per tile (b*32+t): [K: kc12 x key32 x 8elem][V: kc4 x hd96 x 8key] = 6144 shorts
__global__ __launch_bounds__(256) void split_kv_tile(const short* __restrict__ allq,
                                                     const float* __restrict__ bkv,
                                                     short* __restrict__ KVp){
  __shared__ short kv[64*192];
  int bt = blockIdx.x;                 // b*16 + nt64
  int b = bt >> 4;
  int tid = threadIdx.x;
#pragma unroll
  for (int it = 0; it < 6; ++it){
    int c = it*256 + tid;              // 1536 chunks of 16B
    int j = c / 24, cc = c - j*24;
    int token = b*1024 + (bt & 15)*64 + j;
    gload16(allq + (size_t)token*NQP + NQ + cc*8, (char*)kv + (size_t)c*16);
  }
  __syncthreads();
  // K: 768 chunks (2 halves x 12 kc x 32 keys)
#pragma unroll
  for (int it = 0; it < 3; ++it){
    int c = it*256 + tid;
    int h = c / 384, r = c - h*384;
    int kc = r >> 5, j = r & 31;
    bf16x8 v = *reinterpret_cast<const bf16x8*>(&kv[(h*32 + j)*192 + kc*8]);
    bf16x8 o8;
#pragma unroll
    for (int e = 0; e < 8; ++e) o8[e] = f2bf(bf2f(v[e]) + bkv[kc*8 + e]);
    *reinterpret_cast<bf16x8*>(KVp + ((size_t)(bt*2 + h)*6144) + (size_t)(kc*32 + j)*8) = o8;
  }
  // V: 768 chunks (2 halves x 4 kc x 96 hd)
#pragma unroll
  for (int it = 0; it < 3; ++it){
    int c = it*256 + tid;
    int h = c / 384, r = c - h*384;
    int kc = r / 96, hd = r - kc*96;
    float bias = bkv[96 + hd];
    bf16x8 o8;
#pragma unroll
    for (int e = 0; e < 8; ++e)
      o8[e] = f2bf(bf2f(kv[(h*32 + kc*8 + e)*192 + 96 + hd]) + bias);
    *reinterpret_cast<bf16x8*>(KVp + ((size_t)(bt*2 + h)*6144) + 3072 + (size_t)(kc*96 + hd)*8) = o8;
  }
}

// ---------------- flash attention v4: 16 q-rows/wave, 32-key tiles, 2x occupancy ----------------
__global__ __launch_bounds__(256, 4) void attn_fwd(const short* __restrict__ allq,
                                                   const int* __restrict__ topi,
                                                   const float* __restrict__ gates,
                                                   const short* __restrict__ KVp,
                                                   short* __restrict__ o){
  __shared__ short KV[2][6144];        // [K 12x32x8 | V 4x96x8]
  __shared__ short Plds[4][640];       // 16 rows x 40 (pad)
  int qt = blockIdx.x, bh = blockIdx.y;   // qt in [0,16): 64 q-rows per block
  int b = bh >> 3, h = bh & 7;
  int tid = threadIdx.x;
  int lane = tid & 63, w = tid >> 6;
  int l15 = lane & 15, lg = lane >> 4;

  // wave owns 16 q-rows; A-frag row = l15
  int tok0 = b*1024 + qt*64 + w*16;
  int token0 = tok0 + l15;
  int qe = topi[token0*HEADS + h];
  const short* qp = allq + (size_t)token0*NQP + qe*HD;
  bf16x8 qf[3];
#pragma unroll
  for (int t = 0; t < 3; ++t)
    qf[t] = *reinterpret_cast<const bf16x8*>(qp + t*32 + lg*8);

  f32x4 Oacc[6] = {};
  float mrun[4], lrun[4];
#pragma unroll
  for (int r = 0; r < 4; ++r){ mrun[r] = -1.0e30f; lrun[r] = 0.f; }

  const short* kvb = KVp + (size_t)b*32*6144;

  // prologue: stage tile 0
#pragma unroll
  for (int it = 0; it < 3; ++it){
    int c = it*256 + tid;
    gload16(kvb + (size_t)c*8, (char*)&KV[0][0] + (size_t)c*16);
  }
  __syncthreads();

  int cur = 0;
  for (int nt = 0; nt < 32; ++nt){
    if (nt < 31){
      const short* kn = kvb + (size_t)(nt+1)*6144;
#pragma unroll
      for (int it = 0; it < 3; ++it){
        int c = it*256 + tid;
        gload16(kn + (size_t)c*8, (char*)&KV[cur^1][0] + (size_t)c*16);
      }
    }

    // S = Q K^T : rows = wave's 16 q, cols = 32 keys
    f32x4 sa[2];
    __builtin_amdgcn_s_setprio(1);
#pragma unroll
    for (int ct = 0; ct < 2; ++ct){
      f32x4 a = {};
#pragma unroll
      for (int t = 0; t < 3; ++t){
        bf16x8 kf = *reinterpret_cast<const bf16x8*>(&KV[cur][((t*4+lg)*32 + ct*16 + l15)*8]);
        a = __builtin_amdgcn_mfma_f32_16x16x32_bf16(qf[t], kf, a, 0, 0, 0);
      }
      sa[ct] = a;
    }
    __builtin_amdgcn_s_setprio(0);

    // lazy max
    float pmax[4];
    bool need = false;
#pragma unroll
    for (int r = 0; r < 4; ++r){
      pmax[r] = fmaxf(sa[0][r], sa[1][r]);
      need = need || (pmax[r] > mrun[r] + THRRAW);
    }
    if (__any(need)){
#pragma unroll
      for (int r = 0; r < 4; ++r){
        float mx = pmax[r];
#pragma unroll
        for (int d = 1; d < 16; d <<= 1) mx = fmaxf(mx, __shfl_xor(mx, d, 64));
        float mnew = fmaxf(mrun[r], mx);
        float al = exp2f((mrun[r] - mnew)*C2);
        lrun[r] *= al;
#pragma unroll
        for (int dt = 0; dt < 6; ++dt) Oacc[dt][r] *= al;
        mrun[r] = mnew;
      }
    }

    // P = exp2((S-m)*C2); per-lane l partials (reduced once in epilogue)
#pragma unroll
    for (int r = 0; r < 4; ++r){
      float mc = mrun[r]*C2;
      float s = 0.f;
#pragma unroll
      for (int ct = 0; ct < 2; ++ct){
        float p = exp2f(fmaf(sa[ct][r], C2, -mc));
        sa[ct][r] = p; s += p;
      }
      lrun[r] += s;
    }

    // P -> LDS (D-layout -> A-frag layout), then PV
#pragma unroll
    for (int ct = 0; ct < 2; ++ct)
#pragma unroll
      for (int r = 0; r < 4; ++r)
        Plds[w][(lg*4 + r)*40 + ct*16 + l15] = f2bf(sa[ct][r]);

    __builtin_amdgcn_s_setprio(1);
    {
      bf16x8 pa = *reinterpret_cast<const bf16x8*>(&Plds[w][l15*40 + lg*8]);
#pragma unroll
      for (int dt = 0; dt < 6; ++dt){
        bf16x8 vf = *reinterpret_cast<const bf16x8*>(&KV[cur][3072 + ((lg*96) + dt*16 + l15)*8]);
        Oacc[dt] = __builtin_amdgcn_mfma_f32_16x16x32_bf16(pa, vf, Oacc[dt], 0, 0, 0);
      }
    }
    __builtin_amdgcn_s_setprio(0);

    __syncthreads();
    cur ^= 1;
  }

  // epilogue: reduce l across the 16-lane group; fold gate
#pragma unroll
  for (int r = 0; r < 4; ++r){
    float l = lrun[r];
#pragma unroll
    for (int d = 1; d < 16; d <<= 1) l += __shfl_xor(l, d, 64);
    int token = tok0 + lg*4 + r;
    float inv = gates[token*HEADS + h] / l;
#pragma unroll
    for (int dt = 0; dt < 6; ++dt)
      o[(size_t)token*DIM + h*HD + dt*16 + l15] = f2bf(Oacc[dt][r]*inv);
  }
}

// ---------------- launch ----------------
extern "C" void kernel_launch(void* const* d_in, const int* in_sizes, int n_in,
                              void* d_out, int out_size, void* d_ws, size_t ws_size,
                              hipStream_t stream) {
  (void)in_sizes; (void)n_in; (void)out_size; (void)ws_size;
  const float* x    = (const float*)d_in[0];
  const float* Wg   = (const float*)d_in[1];
  const float* W1   = (const float*)d_in[2];
  const float* W2   = (const float*)d_in[3];
  const float* Wkv  = (const float*)d_in[4];
  const float* bkv  = (const float*)d_in[5];
  const int*   task = (const int*)d_in[6];

  char* ws = (char*)d_ws;
  short* xb    = (short*)(ws + OFF_XB);
  short* o     = (short*)(ws + OFF_XB);    // alias: xb dead after GEMM1
  short* Bt1   = (short*)(ws + OFF_BT1);
  short* W2t   = (short*)(ws + OFF_W2T);
  short* KVp   = (short*)(ws + OFF_K);
  float* gates = (float*)(ws + OFF_GATE);
  int*   topi  = (int*)(ws + OFF_TOPI);
  float* aux   = (float*)(ws + OFF_AUX);
  short* allq  = (short*)(ws + OFF_ALLQ);
  float* part  = (float*)(ws + OFF_PART);  // alias: dead before gemm1 writes allq
  float* logT  = (float*)(ws + OFF_LOGT);  // alias: dead before gemm1 writes allq
  float* out   = (float*)d_out;

  hipMemsetAsync(aux, 0, 256, stream);
  prep_kernel   <<<792, 256, 0, stream>>>(W1, Wkv, W2, Bt1, W2t);
  // gating: G1 partials (also emits bf16 x), G2a combine, G2b select+aux
  gating_partial<<<2048, 64, 0, stream>>>(x, Wg, task, xb, part);
  gating_combine<<<768, 256, 0, stream>>>(part, logT);
  gating_select <<<32, 256, 0, stream>>>(logT, topi, gates, aux);
  aux_final     <<<1, 64, 0, stream>>>(aux, out + (size_t)TOK*DIM);
  // all_q (+ kv columns): [8192,768] x [768,2560]
  gemm_bt<true><<<dim3(NQP/128, TOK/128), 256, 0, stream>>>(xb, Bt1, allq, TOK, NQP, DIM);
  split_kv_tile<<<128, 256, 0, stream>>>(allq, bkv, KVp);
  attn_fwd     <<<dim3(16, 64), 256, 0, stream>>>(allq, topi, gates, KVp, o);
  // out = mixed(gated o) @ W2 : [8192,2304] x [2304,768], A built in-kernel
  gemm2_fused  <<<dim3(DIM/64, TOK/128), 256, 0, stream>>>(o, topi, W2t, out);
}